// Round 3
// baseline (596.491 us; speedup 1.0000x reference)
//
#include <hip/hip_runtime.h>

// PositionalEncoding2D gather, MI355X.
//
// pe[e,h,w]: e<768 depends only on w (sin/cos(w*div)), e>=768 only on h,
// and pe[768+k, b, *] == pe[k, 0, b] bit-exactly (same pos/div arrays).
// So the whole 406MB table collapses to v[b][k] = pe[k,0,b] (257x768).
// Build bias-folded tables TW'[b][k]=v+lc[k], TH'[b][k]=v+lc[768+k]
// (1.58MB, L2-resident); each output row = copy of TW'[idx2] ++ TH'[idx1].

#define EMBD   1536
#define HALF   768
#define BINS   257
#define SLAB   (BINS * BINS)   // 66049

// Exact searchsorted(linspace(-5,5,257), clip(x,-5,5-1e-6), side='right').
// Edges edge(i) = (5i-640)/128 are exact in fp32; estimate then correct.
__device__ __forceinline__ int bin_index(float x) {
    const float XMAX = 4.9999990463256836f;  // fp32(5.0 - 1e-6)
    float xc = fminf(fmaxf(x, -5.0f), XMAX);
    int i0 = (int)floorf((xc + 5.0f) * 25.6f);
    i0 = max(0, min(i0, 255));
    // edge(i) = (5*i - 640) * 2^-7, all ops exact in fp32
    while (i0 < 256 && (5.0f * (float)(i0 + 1) - 640.0f) * 0.0078125f <= xc) ++i0;
    while (i0 > 0 && (5.0f * (float)i0 - 640.0f) * 0.0078125f > xc) --i0;
    return i0 + 1;  // in [1, 256]
}

// One block per k in [0,768); threads sweep b (coalesced read of pe[k,0,0..256]).
__global__ __launch_bounds__(320) void build_tables(
    const float* __restrict__ pe, const float* __restrict__ lc,
    float* __restrict__ tw, float* __restrict__ th) {
    int k = blockIdx.x;
    int b = threadIdx.x;
    if (b < BINS) {
        float v = pe[(size_t)k * SLAB + b];      // pe[k, 0, b]
        tw[b * HALF + k] = v + lc[k];
        th[b * HALF + k] = v + lc[HALF + k];
    }
}

// 4 rows per block, 512 threads, 3 float4 per thread.
// Row n: floats [0,768) from TW'[idx2[n]], [768,1536) from TH'[idx1[n]].
__global__ __launch_bounds__(512) void gather_rows(
    const float* __restrict__ x1, const float* __restrict__ x2,
    const float* __restrict__ tw, const float* __restrict__ th,
    float* __restrict__ out) {
    __shared__ int s_i1[4], s_i2[4];
    int n0 = blockIdx.x * 4;
    int t  = threadIdx.x;
    if (t < 4) {
        s_i1[t] = bin_index(x1[n0 + t]);
        s_i2[t] = bin_index(x2[n0 + t]);
    }
    __syncthreads();
#pragma unroll
    for (int j = 0; j < 3; ++j) {
        int fid = t + 512 * j;        // 0..1535 : 4 rows x 384 float4
        int r   = fid / 384;
        int e4  = fid - r * 384;      // 0..383
        const float* src = (e4 < 192)
            ? tw + (size_t)s_i2[r] * HALF + (size_t)e4 * 4
            : th + (size_t)s_i1[r] * HALF + (size_t)(e4 - 192) * 4;
        float4 v = *(const float4*)src;
        *(float4*)(out + (size_t)(n0 + r) * EMBD + (size_t)e4 * 4) = v;
    }
}

extern "C" void kernel_launch(void* const* d_in, const int* in_sizes, int n_in,
                              void* d_out, int out_size, void* d_ws, size_t ws_size,
                              hipStream_t stream) {
    const float* x1 = (const float*)d_in[0];
    const float* x2 = (const float*)d_in[1];
    const float* pe = (const float*)d_in[2];
    const float* lc = (const float*)d_in[3];
    float* out = (float*)d_out;

    float* tw = (float*)d_ws;                 // 257*768 floats
    float* th = tw + (size_t)BINS * HALF;     // 257*768 floats (total 1.58 MB)

    int n = in_sizes[0];                      // 65536
    build_tables<<<HALF, 320, 0, stream>>>(pe, lc, tw, th);
    gather_rows<<<n / 4, 512, 0, stream>>>(x1, x2, tw, th, out);
}